// Round 1
// baseline (721.157 us; speedup 1.0000x reference)
//
#include <hip/hip_runtime.h>
#include <stdint.h>

#define GW 8192
#define GMASK 8191
#define PLANE 67108864ULL   // elements per links plane
#define TPD 128             // tiles per dim (8192/64)
#define TMASK 127
#define NTILES 16384
#define WPR 128             // bitmap words per lattice row

// ---- phase-1 (LDS-resident) parameters ----
#define NSLOT 224           // LDS-cached tiles (224*512B = 112 KB sel storage)
#define HCAP 1024           // hash table entries
#define HMASK 1023
#define QC1 2048            // phase-1 ring entries
#define QM1 2047

// ---- fallback (global-mode) queue ----
#define QCAP 16384
#define QMASK 16383

// ---- workspace layout (byte offsets) ----
#define WS_FILLDONE 0       // u32: fill blocks completed
#define WS_OVER 8           // u32: overflow flag
#define WS_GQN 16           // u32: global overflow-queue count
#define WS_NTILES 24        // u32: touched-tile count (clamped)
#define WS_BITMAP 4096      // 8 MB global sel bitmap (overflow path only)
#define WS_LIST (WS_BITMAP + 8388608)   // u32[NSLOT] tile ids (0xFFFF = leaked)
#define WS_STAG (WS_LIST + 4096)        // u64[NSLOT*64] staged sel rows
#define WS_GQ (WS_STAG + NSLOT * 512)   // u32[16384] overflow tile queue

#define OUT_U4 16777216u    // d_out in uint4s (256 MB)
#define BM_U4 524288u       // bitmap in uint4s (8 MB)

typedef unsigned long long u64;
typedef unsigned int u32;

// ---------------- bit-packing helpers ----------------------------------------
__device__ __forceinline__ u32 nib4(u32 w) {
    return (((w & 0x01010101u) * 0x01020408u) >> 24) & 0xFu;
}
__device__ __forceinline__ u64 pack_row_b8(const unsigned char* p) {
    const uint4* q = (const uint4*)p;
    u64 w = 0;
#pragma unroll
    for (int i = 0; i < 4; i++) {
        uint4 v = q[i];
        u64 nb = (u64)(nib4(v.x) | (nib4(v.y) << 4) | (nib4(v.z) << 8) | (nib4(v.w) << 12));
        w |= nb << (16 * i);
    }
    return w;
}
__device__ __forceinline__ u64 pack_row_b32(const u32* p) {
    u64 w = 0;
#pragma unroll
    for (int k = 0; k < 16; k++) {
        uint4 v = ((const uint4*)p)[k];
        u64 nb = (u64)((v.x != 0) | ((v.y != 0) << 1) | ((v.z != 0) << 2) | ((v.w != 0) << 3));
        w |= nb << (4 * k);
    }
    return w;
}

// ---------------- tiny control-word clear -------------------------------------
__global__ void clear_ctrl_kernel(unsigned char* ws) {
    if (threadIdx.x < 16) ((u32*)ws)[threadIdx.x] = 0;
}

// ---------------- mega kernel: block 0 = LDS BFS, blocks>0 = zero-fill --------
// Fill blocks zero d_out (256 MB) + global bitmap (8 MB) concurrently with the
// BFS. BFS only touches d_out/bitmap via the overflow path, which first waits
// on the fill-done counter (device-scope atomics + fences).
__global__ void __launch_bounds__(1024)
mega_kernel(const unsigned char* __restrict__ links8,
            const int* __restrict__ seed_idx,
            unsigned char* __restrict__ ws,
            uint4* __restrict__ outv) {
    // phase-1 LDS state (allocated in every block; used only by block 0)
    volatile __shared__ unsigned short q[QC1];
    __shared__ u32 tflags[NTILES / 32];
    __shared__ u32 htab[HCAP];              // key = tile | (slot<<14); empty = ~0
    __shared__ u64 selS[NSLOT][64];
    __shared__ unsigned short slot_tile[NSLOT];
    __shared__ int s_qhead, s_qtail, s_active, s_mode, s_c1, s_c3;
    __shared__ int s_nslots, s_over, s_gbready;

    if (blockIdx.x != 0) {
        // ---------------- fill path ----------------
        u32 gtid = (blockIdx.x - 1) * 1024 + threadIdx.x;
        u32 stride = (gridDim.x - 1) * 1024;
        uint4 z = make_uint4(0, 0, 0, 0);
        for (u32 i = gtid; i < OUT_U4; i += stride) outv[i] = z;
        uint4* bm = (uint4*)(ws + WS_BITMAP);
        for (u32 i = gtid; i < BM_U4; i += stride) bm[i] = z;
        __syncthreads();                     // drains vmcnt for every wave
        if (threadIdx.x == 0) {
            __threadfence();
            atomicAdd((u32*)(ws + WS_FILLDONE), 1u);
        }
        return;
    }

    // ---------------- block 0: LDS-resident async tile BFS ----------------
    const int tid = threadIdx.x;
    const int ln = tid & 63;
    const int wv = tid >> 6;

    for (int i = tid; i < QC1; i += 1024) q[i] = 0xFFFF;
    for (int i = tid; i < NTILES / 32; i += 1024) tflags[i] = 0;
    for (int i = tid; i < HCAP; i += 1024) htab[i] = 0xFFFFFFFFu;
    for (int i = tid; i < NSLOT; i += 1024) slot_tile[i] = 0xFFFF;
    for (int i = tid; i < NSLOT * 64; i += 1024) ((u64*)selS)[i] = 0ull;
    if (tid == 0) {
        s_c1 = 0; s_c3 = 0; s_qhead = 0; s_qtail = 0; s_active = 0;
        s_nslots = 0; s_over = 0; s_gbready = 0;
    }
    __syncthreads();

    // ---- detect links encoding (mode 0: byte-bool, else 4-byte words) ----
    int l1c = 0, l3c = 0;
    for (int i = tid; i < 16384; i += 1024) {
        if (links8[i]) { int m = i & 3; if (m == 1) l1c++; else if (m == 3) l3c++; }
    }
    atomicAdd(&s_c1, l1c);
    atomicAdd(&s_c3, l3c);
    __syncthreads();
    if (tid == 0) {
        s_mode = (s_c1 > 0) ? 0 : ((s_c3 > 0) ? 2 : 1);
        int sr = seed_idx[0] & GMASK, sc = seed_idx[1] & GMASK;
        int t = (sr >> 6) * TPD + (sc >> 6);
        s_nslots = 1;
        slot_tile[0] = (unsigned short)t;
        u32 h = ((u32)t * 2654435761u) >> 22;
        htab[h & HMASK] = (u32)t;            // slot 0
        selS[0][sr & 63] = 1ull << (sc & 63);
        tflags[t >> 5] = 1u << (t & 31);
        q[0] = (unsigned short)t;
        s_qtail = 1; s_active = 1;
    }
    __syncthreads();

    const int mode = s_mode;
    const unsigned char* p0b = links8;
    const unsigned char* p1b = links8 + PLANE;
    const u32* p0w = (const u32*)links8;
    const u32* p1w = (const u32*)(links8 + PLANE * 4);
    u64* bitmap = (u64*)(ws + WS_BITMAP);
    const u32 nfill = gridDim.x - 1;

    // find existing slot (entries are never deleted)
    auto find_slot = [&](int t) -> int {
        u32 h = ((u32)t * 2654435761u) >> 22;
        for (int i = 0; i < HCAP; i++) {
            u32 e = ((volatile u32*)htab)[(h + i) & HMASK];
            if (e == 0xFFFFFFFFu) return -1;
            if ((e & 0x3FFFu) == (u32)t) return (int)(e >> 14);
        }
        return -1;
    };
    // find-or-allocate; -1 on slot exhaustion (sticky overflow)
    auto find_or_alloc = [&](int t) -> int {
        u32 h = ((u32)t * 2654435761u) >> 22;
        for (int i = 0; i < HCAP; i++) {
            int idx = (int)((h + i) & HMASK);
            u32 e = ((volatile u32*)htab)[idx];
            if (e == 0xFFFFFFFFu) {
                int s = atomicAdd(&s_nslots, 1);
                if (s >= NSLOT) { s_over = 1; return -1; }
                u32 key = (u32)t | ((u32)s << 14);
                u32 old = atomicCAS(&htab[idx], 0xFFFFFFFFu, key);
                if (old == 0xFFFFFFFFu) { slot_tile[s] = (unsigned short)t; return s; }
                if ((old & 0x3FFFu) == (u32)t) return (int)(old >> 14);
                // lost race to a different tile: slot s leaks (zeroed, skipped)
            } else if ((e & 0x3FFFu) == (u32)t) {
                return (int)(e >> 14);
            }
        }
        s_over = 1; return -1;
    };
    auto enq = [&](int t2) {
        u32 bit = 1u << (t2 & 31);
        u32 old = atomicOr(&tflags[t2 >> 5], bit);
        if (!(old & bit)) {
            atomicAdd(&s_active, 1);             // before ticket: no false-zero
            int pos = atomicAdd(&s_qtail, 1) & QM1;
            q[pos] = (unsigned short)t2;
        }
    };
    auto gq_enq = [&](int t2) {                  // overflow path: global queue
        u32 bit = 1u << (t2 & 31);
        u32 old = atomicOr(&tflags[t2 >> 5], bit);
        if (!(old & bit)) {
            u32 p = atomicAdd((u32*)(ws + WS_GQN), 1u);
            if (p < 16384u) ((u32*)(ws + WS_GQ))[p] = (u32)t2;
        }
    };
    auto gb_wait = [&]() {                       // bitmap usable only post-fill
        if (!s_gbready) {
            while (atomicAdd((u32*)(ws + WS_FILLDONE), 0u) < nfill) {}
            __threadfence();
            s_gbready = 1;
        }
    };

    long long guard = 0;
    while (true) {
        int t = -1;
        if (ln == 0) {
            while (true) {
                if (atomicAdd(&s_active, 0) == 0) break;
                int h = atomicAdd(&s_qhead, 0);
                int tl = atomicAdd(&s_qtail, 0);
                if (h != tl && atomicCAS(&s_qhead, h, h + 1) == h) {
                    int pos = h & QM1;
                    unsigned short v;
                    long long g2 = 0;
                    while ((v = q[pos]) == 0xFFFF) { if (++g2 > 400000000LL) break; }
                    q[pos] = 0xFFFF;
                    t = v;
                    break;
                }
                if (++guard > 400000000LL) break;
            }
        }
        t = __shfl(t, 0);
        if (t < 0) break;

        const int tR = t >> 7, tC = t & TMASK;
        int slot = -1;
        if (ln == 0) slot = find_slot(t);
        slot = __shfl(slot, 0);
        if (slot < 0) { if (ln == 0) atomicSub(&s_active, 1); continue; }

        if (ln == 0) atomicAnd(&tflags[t >> 5], ~(1u << (t & 31)));
        __threadfence_block();   // clear-before-read: late pushes re-enqueue us

        const int gr = tR * 64 + ln;
        u64 loaded = *(volatile u64*)&selS[slot][ln];

        u64 l0, l1;
        if (mode == 0) {
            l0 = pack_row_b8(p0b + (u64)gr * GW + tC * 64);
            l1 = pack_row_b8(p1b + (u64)gr * GW + tC * 64);
        } else {
            l0 = pack_row_b32(p0w + (u64)gr * GW + tC * 64);
            l1 = pack_row_b32(p1w + (u64)gr * GW + tC * 64);
        }

        // ---- in-tile fixpoint: Kogge-Stone run-fill, both axes ----
        u64 P0 = l1 & 0x7FFFFFFFFFFFFFFFull;
        u64 P1 = P0 & (P0 >> 1);
        u64 P2 = P1 & (P1 >> 2);
        u64 P3 = P2 & (P2 >> 4);
        u64 P4 = P3 & (P3 >> 8);
        u64 P5 = P4 & (P4 >> 16);
        u64 D0 = (ln < 63) ? l0 : 0ull;
        u64 D1 = D0 & __shfl_down(D0, 1);
        u64 D2 = D1 & __shfl_down(D1, 2);
        u64 D3 = D2 & __shfl_down(D2, 4);
        u64 D4 = D3 & __shfl_down(D3, 8);
        u64 D5 = D4 & __shfl_down(D4, 16);

        u64 sel = loaded;
        while (true) {
            u64 old = sel;
            sel |= (sel & P0) << 1;  sel |= (sel >> 1)  & P0;
            sel |= (sel & P1) << 2;  sel |= (sel >> 2)  & P1;
            sel |= (sel & P2) << 4;  sel |= (sel >> 4)  & P2;
            sel |= (sel & P3) << 8;  sel |= (sel >> 8)  & P3;
            sel |= (sel & P4) << 16; sel |= (sel >> 16) & P4;
            sel |= (sel & P5) << 32; sel |= (sel >> 32) & P5;
            sel |= __shfl_up(sel & D0, 1);  sel |= __shfl_down(sel, 1)  & D0;
            sel |= __shfl_up(sel & D1, 2);  sel |= __shfl_down(sel, 2)  & D1;
            sel |= __shfl_up(sel & D2, 4);  sel |= __shfl_down(sel, 4)  & D2;
            sel |= __shfl_up(sel & D3, 8);  sel |= __shfl_down(sel, 8)  & D3;
            sel |= __shfl_up(sel & D4, 16); sel |= __shfl_down(sel, 16) & D4;
            sel |= __shfl_up(sel & D5, 32); sel |= __shfl_down(sel, 32) & D5;
            if (__ballot(sel != old) == 0ull) break;
        }

        u64 newbits = sel & ~loaded;
        if (newbits) atomicOr(&selS[slot][ln], newbits);

        // ---- boundary pushes (torus-wrapped), LDS-resident ----
        const int c0 = tC * 64;
        bool rcond = (((sel >> 63) & (l1 >> 63)) & 1ull) != 0;
        u64 lcolb = (u64)((c0 - 1) & GMASK);
        bool lopen = (mode == 0) ? (p1b[(u64)gr * GW + lcolb] != 0)
                                 : (p1w[(u64)gr * GW + lcolb] != 0);
        bool lcond = ((sel & 1ull) != 0) && lopen;
        const int ga = (tR * 64 - 1) & GMASK;
        bool bopen = (mode == 0) ? (p0b[(u64)ga * GW + c0 + ln] != 0)
                                 : (p0w[(u64)ga * GW + c0 + ln] != 0);
        u64 top_sel = __shfl(sel, 0);
        u64 umask = __ballot(bopen && ((top_sel >> ln) & 1));
        u64 dmask = sel & l0;                      // valid on lane 63
        u64 dvote = __shfl(dmask, 63);
        u64 rvote = __ballot(rcond);
        u64 lvote = __ballot(lcond);

        const int tRt = tR * TPD + ((tC + 1) & TMASK);
        const int tLt = tR * TPD + ((tC - 1) & TMASK);
        const int tUt = ((tR - 1) & TMASK) * TPD + tC;
        const int tDt = ((tR + 1) & TMASK) * TPD + tC;

        int sR = -2, sL = -2, sU = -2, sD = -2;
        if (ln == 0) {
            if (rvote) sR = find_or_alloc(tRt);
            if (lvote) sL = find_or_alloc(tLt);
            if (umask) sU = find_or_alloc(tUt);
            if (dvote) sD = find_or_alloc(tDt);
        }
        sR = __shfl(sR, 0); sL = __shfl(sL, 0);
        sU = __shfl(sU, 0); sD = __shfl(sD, 0);

        bool rnew = false, lnew = false;
        u64 unew = 0, dnew = 0;
        if (rvote) {
            if (sR >= 0) {
                if (rcond) { u64 old = atomicOr(&selS[sR][ln], 1ull); rnew = !(old & 1ull); }
            } else {
                gb_wait();
                if (rcond) {
                    u64 old = atomicOr(&bitmap[(u64)gr * WPR + ((tC + 1) & TMASK)], 1ull);
                    rnew = !(old & 1ull);
                }
            }
        }
        if (lvote) {
            if (sL >= 0) {
                if (lcond) { u64 old = atomicOr(&selS[sL][ln], 1ull << 63); lnew = !(old & (1ull << 63)); }
            } else {
                gb_wait();
                if (lcond) {
                    u64 old = atomicOr(&bitmap[(u64)gr * WPR + ((tC - 1) & TMASK)], 1ull << 63);
                    lnew = !(old & (1ull << 63));
                }
            }
        }
        if (umask) {
            if (sU >= 0) {
                if (ln == 0) { u64 old = atomicOr(&selS[sU][63], umask); unew = umask & ~old; }
            } else {
                gb_wait();
                if (ln == 0) { u64 old = atomicOr(&bitmap[(u64)ga * WPR + tC], umask); unew = umask & ~old; }
            }
        }
        if (dvote) {
            if (sD >= 0) {
                if (ln == 63) { u64 old = atomicOr(&selS[sD][0], dmask); dnew = dmask & ~old; }
            } else {
                gb_wait();
                if (ln == 63) {
                    const int gb = (tR * 64 + 64) & GMASK;
                    u64 old = atomicOr(&bitmap[(u64)gb * WPR + tC], dmask);
                    dnew = dmask & ~old;
                }
            }
        }
        u64 rmask = __ballot(rnew), lmask = __ballot(lnew);

        if (ln == 0  && rmask) { if (sR >= 0) enq(tRt); else gq_enq(tRt); }
        if (ln == 1  && lmask) { if (sL >= 0) enq(tLt); else gq_enq(tLt); }
        if (ln == 0  && unew)  { if (sU >= 0) enq(tUt); else gq_enq(tUt); }
        if (ln == 63 && dnew)  { if (sD >= 0) enq(tDt); else gq_enq(tDt); }

        if (ln == 0) atomicSub(&s_active, 1);
    }

    // ---- drain complete: publish results ----
    __syncthreads();
    int ns = s_nslots; if (ns > NSLOT) ns = NSLOT;
    int over = s_over;

    if (over) {
        // flush LDS sel into global bitmap (after fills complete)
        if (tid == 0) {
            while (atomicAdd((u32*)(ws + WS_FILLDONE), 0u) < nfill) {}
            __threadfence();
        }
        __syncthreads();
        for (int s = wv; s < ns; s += 16) {
            int tt = slot_tile[s];
            if (tt == 0xFFFF) continue;
            u64 w = selS[s][ln];
            if (w) atomicOr(&bitmap[(u64)((tt >> 7) * 64 + ln) * WPR + (tt & TMASK)], w);
        }
    } else {
        u64* stag = (u64*)(ws + WS_STAG);
        for (int s = wv; s < ns; s += 16) stag[s * 64 + ln] = selS[s][ln];
    }
    for (int i = tid; i < ns; i += 1024)
        ((u32*)(ws + WS_LIST))[i] = (u32)slot_tile[i];
    if (tid == 0) {
        *(u32*)(ws + WS_NTILES) = (u32)ns;
        *(u32*)(ws + WS_OVER) = (u32)over;
    }
}

// ---------------- fallback: proven global-bitmap BFS (overflow only) ---------
__global__ void __launch_bounds__(1024)
fb_bfs_kernel(const unsigned char* __restrict__ links8,
              unsigned char* __restrict__ ws) {
    __shared__ int s_go;
    volatile __shared__ unsigned short q[QCAP];
    __shared__ u32 tflags[NTILES / 32];
    __shared__ int s_qhead, s_qtail, s_active, s_mode, s_c1, s_c3;

    if (threadIdx.x == 0) s_go = (int)*(volatile u32*)(ws + WS_OVER);
    __syncthreads();
    if (!s_go) return;

    const int tid = threadIdx.x;
    const int ln = tid & 63;
    u64* bitmap = (u64*)(ws + WS_BITMAP);

    for (int i = tid; i < QCAP; i += 1024) q[i] = 0xFFFF;
    for (int i = tid; i < NTILES / 32; i += 1024) tflags[i] = 0;
    if (tid == 0) { s_c1 = 0; s_c3 = 0; s_qhead = 0; s_qtail = 0; s_active = 0; }
    __syncthreads();

    int l1c = 0, l3c = 0;
    for (int i = tid; i < 16384; i += 1024) {
        if (links8[i]) { int m = i & 3; if (m == 1) l1c++; else if (m == 3) l3c++; }
    }
    atomicAdd(&s_c1, l1c);
    atomicAdd(&s_c3, l3c);
    __syncthreads();
    if (tid == 0) s_mode = (s_c1 > 0) ? 0 : ((s_c3 > 0) ? 2 : 1);
    __syncthreads();

    // seed: all LDS-touched tiles + overflow-queued tiles
    {
        u32 ntl = *(u32*)(ws + WS_NTILES);
        u32 gqn = *(u32*)(ws + WS_GQN); if (gqn > 16384u) gqn = 16384u;
        const u32* listp = (const u32*)(ws + WS_LIST);
        const u32* gqp = (const u32*)(ws + WS_GQ);
        for (u32 i = tid; i < ntl + gqn; i += 1024) {
            u32 tt = (i < ntl) ? listp[i] : gqp[i - ntl];
            if (tt == 0xFFFFu) continue;
            int pos = atomicAdd(&s_qtail, 1) & QMASK;
            q[pos] = (unsigned short)tt;
            atomicAdd(&s_active, 1);
            atomicOr(&tflags[tt >> 5], 1u << (tt & 31));
        }
    }
    __syncthreads();

    const int mode = s_mode;
    const unsigned char* p0b = links8;
    const unsigned char* p1b = links8 + PLANE;
    const u32* p0w = (const u32*)links8;
    const u32* p1w = (const u32*)(links8 + PLANE * 4);

    auto enq = [&](int t2) {
        u32 bit = 1u << (t2 & 31);
        u32 old = atomicOr(&tflags[t2 >> 5], bit);
        if (!(old & bit)) {
            atomicAdd(&s_active, 1);
            int pos = atomicAdd(&s_qtail, 1) & QMASK;
            q[pos] = (unsigned short)t2;
        }
    };

    long long guard = 0;
    while (true) {
        int t = -1;
        if (ln == 0) {
            while (true) {
                if (atomicAdd(&s_active, 0) == 0) break;
                int h = atomicAdd(&s_qhead, 0);
                int tl = atomicAdd(&s_qtail, 0);
                if (h != tl && atomicCAS(&s_qhead, h, h + 1) == h) {
                    int pos = h & QMASK;
                    unsigned short v;
                    long long g2 = 0;
                    while ((v = q[pos]) == 0xFFFF) { if (++g2 > 400000000LL) break; }
                    q[pos] = 0xFFFF;
                    t = v;
                    break;
                }
                if (++guard > 400000000LL) break;
            }
        }
        t = __shfl(t, 0);
        if (t < 0) break;

        const int tR = t >> 7, tC = t & TMASK;
        if (ln == 0) atomicAnd(&tflags[t >> 5], ~(1u << (t & 31)));
        __threadfence_block();

        const int gr = tR * 64 + ln;
        u64* wp = &bitmap[(u64)gr * WPR + tC];
        u64 loaded = *(volatile u64*)wp;

        u64 l0, l1;
        if (mode == 0) {
            l0 = pack_row_b8(p0b + (u64)gr * GW + tC * 64);
            l1 = pack_row_b8(p1b + (u64)gr * GW + tC * 64);
        } else {
            l0 = pack_row_b32(p0w + (u64)gr * GW + tC * 64);
            l1 = pack_row_b32(p1w + (u64)gr * GW + tC * 64);
        }

        u64 P0 = l1 & 0x7FFFFFFFFFFFFFFFull;
        u64 P1 = P0 & (P0 >> 1);
        u64 P2 = P1 & (P1 >> 2);
        u64 P3 = P2 & (P2 >> 4);
        u64 P4 = P3 & (P3 >> 8);
        u64 P5 = P4 & (P4 >> 16);
        u64 D0 = (ln < 63) ? l0 : 0ull;
        u64 D1 = D0 & __shfl_down(D0, 1);
        u64 D2 = D1 & __shfl_down(D1, 2);
        u64 D3 = D2 & __shfl_down(D2, 4);
        u64 D4 = D3 & __shfl_down(D3, 8);
        u64 D5 = D4 & __shfl_down(D4, 16);

        u64 sel = loaded;
        while (true) {
            u64 old = sel;
            sel |= (sel & P0) << 1;  sel |= (sel >> 1)  & P0;
            sel |= (sel & P1) << 2;  sel |= (sel >> 2)  & P1;
            sel |= (sel & P2) << 4;  sel |= (sel >> 4)  & P2;
            sel |= (sel & P3) << 8;  sel |= (sel >> 8)  & P3;
            sel |= (sel & P4) << 16; sel |= (sel >> 16) & P4;
            sel |= (sel & P5) << 32; sel |= (sel >> 32) & P5;
            sel |= __shfl_up(sel & D0, 1);  sel |= __shfl_down(sel, 1)  & D0;
            sel |= __shfl_up(sel & D1, 2);  sel |= __shfl_down(sel, 2)  & D1;
            sel |= __shfl_up(sel & D2, 4);  sel |= __shfl_down(sel, 4)  & D2;
            sel |= __shfl_up(sel & D3, 8);  sel |= __shfl_down(sel, 8)  & D3;
            sel |= __shfl_up(sel & D4, 16); sel |= __shfl_down(sel, 16) & D4;
            sel |= __shfl_up(sel & D5, 32); sel |= __shfl_down(sel, 32) & D5;
            if (__ballot(sel != old) == 0ull) break;
        }

        u64 newbits = sel & ~loaded;
        if (newbits) atomicOr(wp, newbits);

        const int c0 = tC * 64;
        bool rnew = false, lnew = false;
        if ((sel >> 63) & (l1 >> 63) & 1ull) {
            u64 old = atomicOr(&bitmap[(u64)gr * WPR + ((tC + 1) & TMASK)], 1ull);
            rnew = !(old & 1ull);
        }
        {
            u64 lcol = (u64)((c0 - 1) & GMASK);
            bool lopen = (mode == 0) ? (p1b[(u64)gr * GW + lcol] != 0)
                                     : (p1w[(u64)gr * GW + lcol] != 0);
            if ((sel & 1ull) && lopen) {
                u64 old = atomicOr(&bitmap[(u64)gr * WPR + ((tC - 1) & TMASK)], 1ull << 63);
                lnew = !(old & (1ull << 63));
            }
        }
        u64 rmask = __ballot(rnew), lmask = __ballot(lnew);

        const int ga = (tR * 64 - 1) & GMASK;
        bool bopen = (mode == 0) ? (p0b[(u64)ga * GW + c0 + ln] != 0)
                                 : (p0w[(u64)ga * GW + c0 + ln] != 0);
        u64 top_sel = __shfl(sel, 0);
        u64 umask = __ballot(bopen && ((top_sel >> ln) & 1));
        u64 unew = 0;
        if (ln == 0 && umask) {
            u64 old = atomicOr(&bitmap[(u64)ga * WPR + tC], umask);
            unew = umask & ~old;
        }
        u64 dmask = sel & l0;
        const int gb = (tR * 64 + 64) & GMASK;
        u64 dnew = 0;
        if (ln == 63 && dmask) {
            u64 old = atomicOr(&bitmap[(u64)gb * WPR + tC], dmask);
            dnew = dmask & ~old;
        }

        if (ln == 0  && rmask) enq(tR * TPD + ((tC + 1) & TMASK));
        if (ln == 1  && lmask) enq(tR * TPD + ((tC - 1) & TMASK));
        if (ln == 0  && unew)  enq(((tR - 1) & TMASK) * TPD + tC);
        if (ln == 63 && dnew)  enq(((tR + 1) & TMASK) * TPD + tC);

        if (ln == 0) atomicSub(&s_active, 1);
    }
}

// ---------------- writeout: staged tiles (fast) or sparse bitmap (overflow) --
__global__ void writeout_kernel(const unsigned char* __restrict__ ws,
                                int* __restrict__ out) {
    __shared__ u32 s_over, s_n;
    if (threadIdx.x == 0) {
        s_over = *(volatile u32*)(ws + WS_OVER);
        s_n = *(volatile u32*)(ws + WS_NTILES);
    }
    __syncthreads();

    if (s_over) {
        // sparse expand of the global bitmap (d_out already zeroed)
        const u64* bitmap = (const u64*)(ws + WS_BITMAP);
        u32 nth = gridDim.x * blockDim.x;
        u32 gt = blockIdx.x * blockDim.x + threadIdx.x;
        for (u32 i = gt; i < 1048576u; i += nth) {
            u64 w = bitmap[i];
            if (!w) continue;
            u64 base = (u64)i << 6;      // == row*8192 + wordcol*64
            while (w) {
                int b = __ffsll((unsigned long long)w) - 1;
                out[base + b] = 1;
                w &= w - 1;
            }
        }
        return;
    }

    if (blockIdx.x >= s_n) return;
    u32 tt = ((const u32*)(ws + WS_LIST))[blockIdx.x];
    if (tt == 0xFFFFu) return;
    const u64* stag = (const u64*)(ws + WS_STAG);
    const int trr = (int)(tt >> 7), tcc = (int)(tt & TMASK);
    int4* ob = (int4*)out;
    for (int i = threadIdx.x; i < 1024; i += 256) {   // 1024 int4 per tile
        int row = i >> 4, c4 = i & 15;
        u64 w = stag[(u64)blockIdx.x * 64 + row];
        u32 nb = (u32)(w >> (c4 * 4)) & 0xFu;
        ob[(u64)(trr * 64 + row) * 2048 + tcc * 16 + c4] =
            make_int4(nb & 1, (nb >> 1) & 1, (nb >> 2) & 1, (nb >> 3) & 1);
    }
}

extern "C" void kernel_launch(void* const* d_in, const int* in_sizes, int n_in,
                              void* d_out, int out_size, void* d_ws, size_t ws_size,
                              hipStream_t stream) {
    const unsigned char* links = (const unsigned char*)d_in[0];
    const int* seed = (const int*)d_in[1];
    unsigned char* ws = (unsigned char*)d_ws;

    clear_ctrl_kernel<<<1, 64, 0, stream>>>(ws);
    mega_kernel<<<2049, 1024, 0, stream>>>(links, seed, ws, (uint4*)d_out);
    fb_bfs_kernel<<<1, 1024, 0, stream>>>(links, ws);
    writeout_kernel<<<NSLOT, 256, 0, stream>>>(ws, (int*)d_out);
}

// Round 2
// 679.814 us; speedup vs baseline: 1.0608x; 1.0608x over previous
//
#include <hip/hip_runtime.h>
#include <stdint.h>

#define GW 8192
#define GMASK 8191
#define PLANE 67108864ULL   // elements per links plane
#define WPR 128             // bitmap words per lattice row

// tiles are 64 rows x 256 cols
#define TPR 128             // tile rows (8192/64)
#define TRMASK 127
#define TPC 32              // tile cols (8192/256)
#define TCMASK 31
#define NTILES 4096
#define QCAP 16384          // ring entries (shorts, 32 KB)
#define QMASK 16383

typedef unsigned long long u64;
typedef unsigned int u32;

// ---------------- clear the 8 MB selection bitmap in ws ----------------------
__global__ void clear_bitmap_kernel(uint4* __restrict__ p, int n) {
    int i = blockIdx.x * blockDim.x + threadIdx.x;
    if (i < n) p[i] = make_uint4(0, 0, 0, 0);
}

// ---------------- bit-packing helpers ----------------------------------------
__device__ __forceinline__ u32 nib4(u32 w) {
    return (((w & 0x01010101u) * 0x01020408u) >> 24) & 0xFu;
}
__device__ __forceinline__ u64 pack_row_b8(const unsigned char* p) {
    const uint4* q = (const uint4*)p;
    u64 w = 0;
#pragma unroll
    for (int i = 0; i < 4; i++) {
        uint4 v = q[i];
        u64 nb = (u64)(nib4(v.x) | (nib4(v.y) << 4) | (nib4(v.z) << 8) | (nib4(v.w) << 12));
        w |= nb << (16 * i);
    }
    return w;
}
__device__ __forceinline__ u64 pack_row_b32(const u32* p) {
    u64 w = 0;
#pragma unroll
    for (int k = 0; k < 16; k++) {
        uint4 v = ((const uint4*)p)[k];
        u64 nb = (u64)((v.x != 0) | ((v.y != 0) << 1) | ((v.z != 0) << 2) | ((v.w != 0) << 3));
        w |= nb << (4 * k);
    }
    return w;
}

// horizontal Kogge-Stone run-fill within one 64-bit word
#define HFILL(S, Pa, Pb, Pc, Pd, Pe, Pf) \
    S |= (S & Pa) << 1;  S |= (S >> 1)  & Pa; \
    S |= (S & Pb) << 2;  S |= (S >> 2)  & Pb; \
    S |= (S & Pc) << 4;  S |= (S >> 4)  & Pc; \
    S |= (S & Pd) << 8;  S |= (S >> 8)  & Pd; \
    S |= (S & Pe) << 16; S |= (S >> 16) & Pe; \
    S |= (S & Pf) << 32; S |= (S >> 32) & Pf;

// vertical Kogge-Stone run-fill across lanes (rows)
#define VFILL(S, Da, Db, Dc, Dd, De, Df) \
    S |= __shfl_up(S & Da, 1);  S |= __shfl_down(S, 1)  & Da; \
    S |= __shfl_up(S & Db, 2);  S |= __shfl_down(S, 2)  & Db; \
    S |= __shfl_up(S & Dc, 4);  S |= __shfl_down(S, 4)  & Dc; \
    S |= __shfl_up(S & Dd, 8);  S |= __shfl_down(S, 8)  & Dd; \
    S |= __shfl_up(S & De, 16); S |= __shfl_down(S, 16) & De; \
    S |= __shfl_up(S & Df, 32); S |= __shfl_down(S, 32) & Df;

#define MKP(l, P0, P1, P2, P3, P4, P5) \
    u64 P0 = (l) & 0x7FFFFFFFFFFFFFFFull; \
    u64 P1 = P0 & (P0 >> 1);  u64 P2 = P1 & (P1 >> 2); \
    u64 P3 = P2 & (P2 >> 4);  u64 P4 = P3 & (P3 >> 8); \
    u64 P5 = P4 & (P4 >> 16);

#define MKD(l, D0, D1, D2, D3, D4, D5) \
    u64 D0 = (ln < 63) ? (l) : 0ull; \
    u64 D1 = D0 & __shfl_down(D0, 1);  u64 D2 = D1 & __shfl_down(D1, 2); \
    u64 D3 = D2 & __shfl_down(D2, 4);  u64 D4 = D3 & __shfl_down(D3, 8); \
    u64 D5 = D4 & __shfl_down(D4, 16);

// cross-word carry: bond = 0/1 mask for the boundary bond between Sa bit63 and Sb bit0
#define XW(Sa, Sb, bond) \
    Sb |= (Sa >> 63) & (bond); Sa |= ((Sb & 1ull) & (bond)) << 63;

// ---------------- single-block ASYNC tile-granular BFS ------------------------
// One wave processes one 64x256 tile; tiles flow through a shared ring queue
// (no per-level barriers). Global bitmap is monotone (atomicOr only).
// Re-enqueue protocol: clear tflag BEFORE reading bitmap; pushers set tflag
// after their bitmap atomicOr completes (forced by using the returned old).
__global__ void __launch_bounds__(512)
bfs_tiles_kernel(const unsigned char* __restrict__ links8,
                 const int* __restrict__ seed_idx,
                 u64* __restrict__ bitmap) {
    volatile __shared__ unsigned short q[QCAP];
    __shared__ u32 tflags[NTILES / 32];
    __shared__ int s_qhead, s_qtail, s_active, s_mode, s_c1, s_c3;

    const int tid = threadIdx.x;
    const int ln  = tid & 63;

    for (int i = tid; i < QCAP; i += 512) q[i] = 0xFFFF;
    for (int i = tid; i < NTILES / 32; i += 512) tflags[i] = 0;
    if (tid == 0) { s_c1 = 0; s_c3 = 0; s_qhead = 0; s_qtail = 0; s_active = 0; }
    __syncthreads();

    // ---- detect links encoding (mode 0: byte-bool, 1: int32, 2: float32) ----
    int l1c = 0, l3c = 0;
    for (int i = tid; i < 16384; i += 512) {
        if (links8[i]) { int m = i & 3; if (m == 1) l1c++; else if (m == 3) l3c++; }
    }
    atomicAdd(&s_c1, l1c);
    atomicAdd(&s_c3, l3c);
    __syncthreads();
    if (tid == 0) {
        s_mode = (s_c1 > 0) ? 0 : ((s_c3 > 0) ? 2 : 1);
        int sr = seed_idx[0] & GMASK, sc = seed_idx[1] & GMASK;
        atomicOr(&bitmap[(u64)sr * WPR + (sc >> 6)], 1ull << (sc & 63));
        int t = (sr >> 6) * TPC + (sc >> 8);
        tflags[t >> 5] = 1u << (t & 31);
        q[0] = (unsigned short)t;
        s_qtail = 1; s_active = 1;
    }
    __syncthreads();

    const int mode = s_mode;
    const unsigned char* p0b = links8;
    const unsigned char* p1b = links8 + PLANE;
    const u32* p0w = (const u32*)links8;
    const u32* p1w = (const u32*)(links8 + PLANE * 4);

    auto enq = [&](int t2) {
        u32 bit = 1u << (t2 & 31);
        u32 old = atomicOr(&tflags[t2 >> 5], bit);
        if (!(old & bit)) {
            atomicAdd(&s_active, 1);               // before ticket: no false-zero
            int pos = atomicAdd(&s_qtail, 1) & QMASK;
            q[pos] = (unsigned short)t2;           // publish (sentinel scheme)
        }
    };

    long long guard = 0;
    while (true) {
        int t = -1;
        if (ln == 0) {
            while (true) {
                if (atomicAdd(&s_active, 0) == 0) break;          // all done
                int h  = atomicAdd(&s_qhead, 0);
                int tl = atomicAdd(&s_qtail, 0);
                if (h != tl && atomicCAS(&s_qhead, h, h + 1) == h) {
                    int pos = h & QMASK;
                    unsigned short v;
                    long long g2 = 0;
                    while ((v = q[pos]) == 0xFFFF) { if (++g2 > 400000000LL) break; }
                    q[pos] = 0xFFFF;                              // release slot
                    t = v;
                    break;
                }
                if (++guard > 400000000LL) break;                 // failsafe
            }
        }
        t = __shfl(t, 0);
        if (t < 0) break;

        const int tR = t >> 5, tCc = t & TCMASK;
        if (ln == 0) atomicAnd(&tflags[t >> 5], ~(1u << (t & 31)));
        __threadfence_block();   // clear-before-read: late pushes re-enqueue us

        const int gr = tR * 64 + ln;         // this lane's global row
        const int c0 = tCc * 256;            // tile's first column
        const int w0 = tCc * 4;              // tile's first bitmap word
        u64* wp = &bitmap[(u64)gr * WPR + w0];
        u64 ld0v = ((volatile u64*)wp)[0];
        u64 ld1v = ((volatile u64*)wp)[1];
        u64 ld2v = ((volatile u64*)wp)[2];
        u64 ld3v = ((volatile u64*)wp)[3];

        u64 l0_0, l0_1, l0_2, l0_3;          // vertical bonds (axis 0)
        u64 l1_0, l1_1, l1_2, l1_3;          // horizontal bonds (axis 1)
        if (mode == 0) {
            const unsigned char* r0 = p0b + (u64)gr * GW + c0;
            const unsigned char* r1 = p1b + (u64)gr * GW + c0;
            l0_0 = pack_row_b8(r0);       l0_1 = pack_row_b8(r0 + 64);
            l0_2 = pack_row_b8(r0 + 128); l0_3 = pack_row_b8(r0 + 192);
            l1_0 = pack_row_b8(r1);       l1_1 = pack_row_b8(r1 + 64);
            l1_2 = pack_row_b8(r1 + 128); l1_3 = pack_row_b8(r1 + 192);
        } else {
            const u32* r0 = p0w + (u64)gr * GW + c0;
            const u32* r1 = p1w + (u64)gr * GW + c0;
            l0_0 = pack_row_b32(r0);       l0_1 = pack_row_b32(r0 + 64);
            l0_2 = pack_row_b32(r0 + 128); l0_3 = pack_row_b32(r0 + 192);
            l1_0 = pack_row_b32(r1);       l1_1 = pack_row_b32(r1 + 64);
            l1_2 = pack_row_b32(r1 + 128); l1_3 = pack_row_b32(r1 + 192);
        }

        // cross-word bonds (bit63 of words 0..2) and cross-tile right bond
        const u64 cw01 = (l1_0 >> 63) & 1ull;
        const u64 cw12 = (l1_1 >> 63) & 1ull;
        const u64 cw23 = (l1_2 >> 63) & 1ull;
        const bool rbond = ((l1_3 >> 63) & 1ull) != 0;

        // ---- in-tile fixpoint: Kogge-Stone run-fill, both axes, 4 words ----
        MKP(l1_0, P0_0, P1_0, P2_0, P3_0, P4_0, P5_0);
        MKP(l1_1, P0_1, P1_1, P2_1, P3_1, P4_1, P5_1);
        MKP(l1_2, P0_2, P1_2, P2_2, P3_2, P4_2, P5_2);
        MKP(l1_3, P0_3, P1_3, P2_3, P3_3, P4_3, P5_3);
        MKD(l0_0, D0_0, D1_0, D2_0, D3_0, D4_0, D5_0);
        MKD(l0_1, D0_1, D1_1, D2_1, D3_1, D4_1, D5_1);
        MKD(l0_2, D0_2, D1_2, D2_2, D3_2, D4_2, D5_2);
        MKD(l0_3, D0_3, D1_3, D2_3, D3_3, D4_3, D5_3);

        u64 sel0 = ld0v, sel1 = ld1v, sel2 = ld2v, sel3 = ld3v;
        while (true) {
            u64 o0 = sel0, o1 = sel1, o2 = sel2, o3 = sel3;
            HFILL(sel0, P0_0, P1_0, P2_0, P3_0, P4_0, P5_0);
            HFILL(sel1, P0_1, P1_1, P2_1, P3_1, P4_1, P5_1);
            HFILL(sel2, P0_2, P1_2, P2_2, P3_2, P4_2, P5_2);
            HFILL(sel3, P0_3, P1_3, P2_3, P3_3, P4_3, P5_3);
            XW(sel0, sel1, cw01);
            XW(sel1, sel2, cw12);
            XW(sel2, sel3, cw23);
            XW(sel1, sel2, cw12);
            XW(sel0, sel1, cw01);
            VFILL(sel0, D0_0, D1_0, D2_0, D3_0, D4_0, D5_0);
            VFILL(sel1, D0_1, D1_1, D2_1, D3_1, D4_1, D5_1);
            VFILL(sel2, D0_2, D1_2, D2_2, D3_2, D4_2, D5_2);
            VFILL(sel3, D0_3, D1_3, D2_3, D3_3, D4_3, D5_3);
            u64 ch = (sel0 ^ o0) | (sel1 ^ o1) | (sel2 ^ o2) | (sel3 ^ o3);
            if (__ballot(ch != 0ull) == 0ull) break;
        }

        // write back own new bits (atomicOr: never erase concurrent pushes)
        u64 nb0 = sel0 & ~ld0v; if (nb0) atomicOr(wp + 0, nb0);
        u64 nb1 = sel1 & ~ld1v; if (nb1) atomicOr(wp + 1, nb1);
        u64 nb2 = sel2 & ~ld2v; if (nb2) atomicOr(wp + 2, nb2);
        u64 nb3 = sel3 & ~ld3v; if (nb3) atomicOr(wp + 3, nb3);

        // ---- boundary pushes (torus-wrapped); enqueue only on genuinely-new.
        // Using the returned old forces vmcnt-completion before the LDS enq.
        // right push (bond at col c0+255 = l1_3 bit63)
        bool rnew = false;
        if (((sel3 >> 63) & 1ull) && rbond) {
            u64 old = atomicOr(&bitmap[(u64)gr * WPR + ((tCc + 1) & TCMASK) * 4], 1ull);
            rnew = !(old & 1ull);
        }
        // left push (bond at global col c0-1), gather predicated on sel bit 0
        bool lnew = false;
        if (sel0 & 1ull) {
            u64 lcol = (u64)((c0 - 1) & GMASK);
            bool lopen = (mode == 0) ? (p1b[(u64)gr * GW + lcol] != 0)
                                     : (p1w[(u64)gr * GW + lcol] != 0);
            if (lopen) {
                u64 old = atomicOr(&bitmap[(u64)gr * WPR + ((tCc - 1) & TCMASK) * 4 + 3],
                                   1ull << 63);
                lnew = !(old & (1ull << 63));
            }
        }
        u64 rmask = __ballot(rnew), lmask = __ballot(lnew);

        // up push: row above tile; per-word masks, loads predicated on top-row bits
        const int ga = (tR * 64 - 1) & GMASK;
        u64 um0 = 0, um1 = 0, um2 = 0, um3 = 0;
        {
            u64 ts;
            ts = __shfl(sel0, 0);
            if (ts) um0 = __ballot(((ts >> ln) & 1) &&
                ((mode == 0) ? (p0b[(u64)ga * GW + c0 + ln] != 0)
                             : (p0w[(u64)ga * GW + c0 + ln] != 0)));
            ts = __shfl(sel1, 0);
            if (ts) um1 = __ballot(((ts >> ln) & 1) &&
                ((mode == 0) ? (p0b[(u64)ga * GW + c0 + 64 + ln] != 0)
                             : (p0w[(u64)ga * GW + c0 + 64 + ln] != 0)));
            ts = __shfl(sel2, 0);
            if (ts) um2 = __ballot(((ts >> ln) & 1) &&
                ((mode == 0) ? (p0b[(u64)ga * GW + c0 + 128 + ln] != 0)
                             : (p0w[(u64)ga * GW + c0 + 128 + ln] != 0)));
            ts = __shfl(sel3, 0);
            if (ts) um3 = __ballot(((ts >> ln) & 1) &&
                ((mode == 0) ? (p0b[(u64)ga * GW + c0 + 192 + ln] != 0)
                             : (p0w[(u64)ga * GW + c0 + 192 + ln] != 0)));
        }
        u64 myum = (ln == 0) ? um0 : (ln == 1) ? um1 : (ln == 2) ? um2 : (ln == 3) ? um3 : 0;
        u64 unew = 0;
        if (ln < 4 && myum) {
            u64 old = atomicOr(&bitmap[(u64)ga * WPR + w0 + ln], myum);
            unew = myum & ~old;
        }
        u64 uany = __ballot(unew != 0);

        // down push: row below tile; dmask from lane 63's in-register bonds
        const int gb = (tR * 64 + 64) & GMASK;
        u64 dm0 = __shfl(sel0 & l0_0, 63);
        u64 dm1 = __shfl(sel1 & l0_1, 63);
        u64 dm2 = __shfl(sel2 & l0_2, 63);
        u64 dm3 = __shfl(sel3 & l0_3, 63);
        u64 mydm = (ln == 4) ? dm0 : (ln == 5) ? dm1 : (ln == 6) ? dm2 : (ln == 7) ? dm3 : 0;
        u64 dnew = 0;
        if (ln >= 4 && ln < 8 && mydm) {
            u64 old = atomicOr(&bitmap[(u64)gb * WPR + w0 + (ln - 4)], mydm);
            dnew = mydm & ~old;
        }
        u64 dany = __ballot(dnew != 0);

        if (ln == 0 && rmask) enq(tR * TPC + ((tCc + 1) & TCMASK));
        if (ln == 1 && lmask) enq(tR * TPC + ((tCc - 1) & TCMASK));
        if (ln == 2 && uany)  enq(((tR - 1) & TRMASK) * TPC + tCc);
        if (ln == 3 && dany)  enq(((tR + 1) & TRMASK) * TPC + tCc);

        // done with this tile (all lanes' enq atomics precede in program order)
        if (ln == 0) atomicSub(&s_active, 1);
    }
}

// ---------------- expand bitmap -> int32 output (write-bound, 256 MB) --------
__global__ void writeout_kernel(const u64* __restrict__ bitmap, int4* __restrict__ out) {
    int g = blockIdx.x * blockDim.x + threadIdx.x;  // int4 index
    int site0 = g << 2;
    u64 w = bitmap[site0 >> 6];
    u32 b = (u32)(w >> (site0 & 63)) & 0xFu;
    out[g] = make_int4(b & 1, (b >> 1) & 1, (b >> 2) & 1, (b >> 3) & 1);
}

extern "C" void kernel_launch(void* const* d_in, const int* in_sizes, int n_in,
                              void* d_out, int out_size, void* d_ws, size_t ws_size,
                              hipStream_t stream) {
    const unsigned char* links = (const unsigned char*)d_in[0];
    const int* seed = (const int*)d_in[1];

    u64* bitmap = (u64*)((char*)d_ws + 4096);   // 8 MB

    clear_bitmap_kernel<<<2048, 256, 0, stream>>>((uint4*)bitmap, 524288);
    bfs_tiles_kernel<<<1, 512, 0, stream>>>(links, seed, bitmap);
    writeout_kernel<<<65536, 256, 0, stream>>>(bitmap, (int4*)d_out);
}

// Round 3
// 654.677 us; speedup vs baseline: 1.1015x; 1.0384x over previous
//
#include <hip/hip_runtime.h>
#include <stdint.h>

#define GW 8192
#define GMASK 8191
#define PLANE 67108864ULL   // elements per links plane
#define TPD 128             // tiles per dim (8192/64)
#define TMASK 127
#define NTILES 16384
#define QCAP 16384          // ring entries (shorts, 32 KB)
#define QMASK 16383
#define WPR 128             // bitmap words per lattice row

// workspace layout
#define WS_BITMAP 4096                      // 8 MB selection bitmap
#define WS_TFEVER (WS_BITMAP + 8388608)     // 2 KB ever-touched tile bitmap

#define OUT_U4 16777216u    // d_out in uint4s (256 MB)

typedef unsigned long long u64;
typedef unsigned int u32;

// ---------------- clear the 8 MB selection bitmap in ws ----------------------
__global__ void clear_bitmap_kernel(uint4* __restrict__ p, int n) {
    int i = blockIdx.x * blockDim.x + threadIdx.x;
    if (i < n) p[i] = make_uint4(0, 0, 0, 0);
}

// ---------------- bit-packing helpers ----------------------------------------
__device__ __forceinline__ u32 nib4(u32 w) {
    return (((w & 0x01010101u) * 0x01020408u) >> 24) & 0xFu;
}
__device__ __forceinline__ u64 pack_row_b8(const unsigned char* p) {
    const uint4* q = (const uint4*)p;
    u64 w = 0;
#pragma unroll
    for (int i = 0; i < 4; i++) {
        uint4 v = q[i];
        u64 nb = (u64)(nib4(v.x) | (nib4(v.y) << 4) | (nib4(v.z) << 8) | (nib4(v.w) << 12));
        w |= nb << (16 * i);
    }
    return w;
}
__device__ __forceinline__ u64 pack_row_b32(const u32* p) {
    u64 w = 0;
#pragma unroll
    for (int k = 0; k < 16; k++) {
        uint4 v = ((const uint4*)p)[k];
        u64 nb = (u64)((v.x != 0) | ((v.y != 0) << 1) | ((v.z != 0) << 2) | ((v.w != 0) << 3));
        w |= nb << (4 * k);
    }
    return w;
}

// ---------------- mega kernel: block 0 = async tile BFS, blocks>0 = out-zero --
// Fill blocks zero d_out (256 MB) concurrently with the BFS (no coupling at
// all: the sparse writeout that needs the zeros runs in a LATER kernel).
// BFS block is the proven R0 structure: one wave per 64x64 tile, shared ring
// queue, monotone global bitmap (atomicOr only), clear-tflag-before-read
// re-enqueue protocol, push-then-enq ordering via the returned old value.
__global__ void __launch_bounds__(1024)
mega_kernel(const unsigned char* __restrict__ links8,
            const int* __restrict__ seed_idx,
            unsigned char* __restrict__ ws,
            uint4* __restrict__ outv) {
    volatile __shared__ unsigned short q[QCAP];
    __shared__ u32 tflags[NTILES / 32];
    __shared__ u32 tfever[NTILES / 32];     // never cleared: tiles ever enqueued
    __shared__ int s_qhead, s_qtail, s_active, s_mode, s_c1, s_c3;

    if (blockIdx.x != 0) {
        // ---------------- fill path: zero d_out ----------------
        u32 gtid = (blockIdx.x - 1) * 1024 + threadIdx.x;
        u32 stride = (gridDim.x - 1) * 1024;
        uint4 z = make_uint4(0, 0, 0, 0);
        for (u32 i = gtid; i < OUT_U4; i += stride) outv[i] = z;
        return;
    }

    u64* bitmap = (u64*)(ws + WS_BITMAP);
    const int tid = threadIdx.x;
    const int ln  = tid & 63;

    for (int i = tid; i < QCAP; i += 1024) q[i] = 0xFFFF;
    for (int i = tid; i < NTILES / 32; i += 1024) { tflags[i] = 0; tfever[i] = 0; }
    if (tid == 0) { s_c1 = 0; s_c3 = 0; s_qhead = 0; s_qtail = 0; s_active = 0; }
    __syncthreads();

    // ---- detect links encoding (mode 0: byte-bool, 1: int32, 2: float32) ----
    int l1c = 0, l3c = 0;
    for (int i = tid; i < 16384; i += 1024) {
        if (links8[i]) { int m = i & 3; if (m == 1) l1c++; else if (m == 3) l3c++; }
    }
    atomicAdd(&s_c1, l1c);
    atomicAdd(&s_c3, l3c);
    __syncthreads();
    if (tid == 0) {
        s_mode = (s_c1 > 0) ? 0 : ((s_c3 > 0) ? 2 : 1);
        int sr = seed_idx[0] & GMASK, sc = seed_idx[1] & GMASK;
        atomicOr(&bitmap[(u64)sr * WPR + (sc >> 6)], 1ull << (sc & 63));
        int t = (sr >> 6) * TPD + (sc >> 6);
        tflags[t >> 5] = 1u << (t & 31);
        tfever[t >> 5] = 1u << (t & 31);
        q[0] = (unsigned short)t;
        s_qtail = 1; s_active = 1;
    }
    __syncthreads();

    const int mode = s_mode;
    const unsigned char* p0b = links8;
    const unsigned char* p1b = links8 + PLANE;
    const u32* p0w = (const u32*)links8;
    const u32* p1w = (const u32*)(links8 + PLANE * 4);

    auto enq = [&](int t2) {
        u32 bit = 1u << (t2 & 31);
        atomicOr(&tfever[t2 >> 5], bit);           // ever-touched (sparse writeout)
        u32 old = atomicOr(&tflags[t2 >> 5], bit);
        if (!(old & bit)) {
            atomicAdd(&s_active, 1);               // before ticket: no false-zero
            int pos = atomicAdd(&s_qtail, 1) & QMASK;
            q[pos] = (unsigned short)t2;           // publish (sentinel scheme)
        }
    };

    long long guard = 0;
    while (true) {
        int t = -1;
        if (ln == 0) {
            while (true) {
                if (atomicAdd(&s_active, 0) == 0) break;          // all done
                int h  = atomicAdd(&s_qhead, 0);
                int tl = atomicAdd(&s_qtail, 0);
                if (h != tl && atomicCAS(&s_qhead, h, h + 1) == h) {
                    int pos = h & QMASK;
                    unsigned short v;
                    long long g2 = 0;
                    while ((v = q[pos]) == 0xFFFF) { if (++g2 > 400000000LL) break; }
                    q[pos] = 0xFFFF;                              // release slot
                    t = v;
                    break;
                }
                if (++guard > 400000000LL) break;                 // failsafe
            }
        }
        t = __shfl(t, 0);
        if (t < 0) break;

        const int tR = t >> 7, tC = t & TMASK;
        if (ln == 0) atomicAnd(&tflags[t >> 5], ~(1u << (t & 31)));
        __threadfence_block();   // clear-before-read: late pushes re-enqueue us

        const int gr = tR * 64 + ln;         // this lane's global row
        u64* wp = &bitmap[(u64)gr * WPR + tC];
        u64 loaded = *(volatile u64*)wp;

        u64 l0, l1;                          // packed bonds for this row
        if (mode == 0) {
            l0 = pack_row_b8(p0b + (u64)gr * GW + tC * 64);
            l1 = pack_row_b8(p1b + (u64)gr * GW + tC * 64);
        } else {
            l0 = pack_row_b32(p0w + (u64)gr * GW + tC * 64);
            l1 = pack_row_b32(p1w + (u64)gr * GW + tC * 64);
        }

        // ---- in-tile fixpoint: Kogge-Stone run-fill, both axes ----
        // P[i]: can jump c -> c+2^i horizontally (in-tile bonds only)
        u64 P0 = l1 & 0x7FFFFFFFFFFFFFFFull;          // drop boundary bond 63
        u64 P1 = P0 & (P0 >> 1);
        u64 P2 = P1 & (P1 >> 2);
        u64 P3 = P2 & (P2 >> 4);
        u64 P4 = P3 & (P3 >> 8);
        u64 P5 = P4 & (P4 >> 16);
        // D[i]: lane r can jump r -> r+2^i vertically (in-tile bonds only)
        u64 D0 = (ln < 63) ? l0 : 0ull;
        u64 D1 = D0 & __shfl_down(D0, 1);
        u64 D2 = D1 & __shfl_down(D1, 2);
        u64 D3 = D2 & __shfl_down(D2, 4);
        u64 D4 = D3 & __shfl_down(D3, 8);
        u64 D5 = D4 & __shfl_down(D4, 16);

        u64 sel = loaded;
        while (true) {
            u64 old = sel;
            // horizontal full run-fill (6 doubling rounds, both directions)
            sel |= (sel & P0) << 1;  sel |= (sel >> 1)  & P0;
            sel |= (sel & P1) << 2;  sel |= (sel >> 2)  & P1;
            sel |= (sel & P2) << 4;  sel |= (sel >> 4)  & P2;
            sel |= (sel & P3) << 8;  sel |= (sel >> 8)  & P3;
            sel |= (sel & P4) << 16; sel |= (sel >> 16) & P4;
            sel |= (sel & P5) << 32; sel |= (sel >> 32) & P5;
            // vertical full run-fill
            sel |= __shfl_up(sel & D0, 1);  sel |= __shfl_down(sel, 1)  & D0;
            sel |= __shfl_up(sel & D1, 2);  sel |= __shfl_down(sel, 2)  & D1;
            sel |= __shfl_up(sel & D2, 4);  sel |= __shfl_down(sel, 4)  & D2;
            sel |= __shfl_up(sel & D3, 8);  sel |= __shfl_down(sel, 8)  & D3;
            sel |= __shfl_up(sel & D4, 16); sel |= __shfl_down(sel, 16) & D4;
            sel |= __shfl_up(sel & D5, 32); sel |= __shfl_down(sel, 32) & D5;
            if (__ballot(sel != old) == 0ull) break;
        }

        // write back own new bits (atomicOr: never erase concurrent pushes)
        u64 newbits = sel & ~loaded;
        if (newbits) atomicOr(wp, newbits);

        // ---- boundary pushes (torus-wrapped); enqueue only on genuinely-new.
        // Using the returned old forces vmcnt-completion before the LDS enq.
        const int c0 = tC * 64;
        bool rnew = false, lnew = false;
        if ((sel >> 63) & (l1 >> 63) & 1ull) {       // bond c0+63: push right
            u64 old = atomicOr(&bitmap[(u64)gr * WPR + ((tC + 1) & TMASK)], 1ull);
            rnew = !(old & 1ull);
        }
        if (sel & 1ull) {                            // bond (gr, c0-1): push left
            // gather predicated on sel bit 0: skips a 64-cache-line gather
            u64 lcol = (u64)((c0 - 1) & GMASK);
            bool lopen = (mode == 0) ? (p1b[(u64)gr * GW + lcol] != 0)
                                     : (p1w[(u64)gr * GW + lcol] != 0);
            if (lopen) {
                u64 old = atomicOr(&bitmap[(u64)gr * WPR + ((tC - 1) & TMASK)], 1ull << 63);
                lnew = !(old & (1ull << 63));
            }
        }
        u64 rmask = __ballot(rnew), lmask = __ballot(lnew);

        const int ga = (tR * 64 - 1) & GMASK;        // row above tile
        u64 top_sel = __shfl(sel, 0);
        u64 umask = 0;
        if (top_sel) {                               // predicated on nonempty top row
            bool bopen = ((top_sel >> ln) & 1) &&
                ((mode == 0) ? (p0b[(u64)ga * GW + c0 + ln] != 0)
                             : (p0w[(u64)ga * GW + c0 + ln] != 0));
            umask = __ballot(bopen);
        }
        u64 unew = 0;
        if (ln == 0 && umask) {
            u64 old = atomicOr(&bitmap[(u64)ga * WPR + tC], umask);
            unew = umask & ~old;
        }
        u64 dmask = sel & l0;                        // valid on lane 63
        const int gb = (tR * 64 + 64) & GMASK;       // row below tile
        u64 dnew = 0;
        if (ln == 63 && dmask) {
            u64 old = atomicOr(&bitmap[(u64)gb * WPR + tC], dmask);
            dnew = dmask & ~old;
        }

        if (ln == 0  && rmask) enq(tR * TPD + ((tC + 1) & TMASK));
        if (ln == 1  && lmask) enq(tR * TPD + ((tC - 1) & TMASK));
        if (ln == 0  && unew)  enq(((tR - 1) & TMASK) * TPD + tC);
        if (ln == 63 && dnew)  enq(((tR + 1) & TMASK) * TPD + tC);

        // done with this tile (all lanes' enq atomics precede in program order)
        if (ln == 0) atomicSub(&s_active, 1);
    }

    // ---- flush ever-touched tile set for the sparse writeout ----
    __syncthreads();
    for (int i = tid; i < NTILES / 32; i += 1024)
        ((u32*)(ws + WS_TFEVER))[i] = tfever[i];
}

// ---------------- sparse writeout: expand only ever-touched tiles ------------
// d_out was zeroed by the mega kernel's fill blocks (stream-ordered earlier).
__global__ void __launch_bounds__(256)
writeout_sparse(const unsigned char* __restrict__ ws, int4* __restrict__ ob) {
    const u64* bitmap = (const u64*)(ws + WS_BITMAP);
    const u32* tf = (const u32*)(ws + WS_TFEVER);
    for (int t = blockIdx.x; t < NTILES; t += gridDim.x) {
        if (!((tf[t >> 5] >> (t & 31)) & 1u)) continue;
        int tR = t >> 7, tC = t & TMASK;
        for (int i = threadIdx.x; i < 1024; i += 256) {   // 1024 int4 per tile
            int row = i >> 4, c4 = i & 15;
            u64 w = bitmap[(u64)(tR * 64 + row) * WPR + tC];
            u32 nb = (u32)(w >> (c4 * 4)) & 0xFu;
            ob[(u64)(tR * 64 + row) * 2048 + tC * 16 + c4] =
                make_int4(nb & 1, (nb >> 1) & 1, (nb >> 2) & 1, (nb >> 3) & 1);
        }
    }
}

extern "C" void kernel_launch(void* const* d_in, const int* in_sizes, int n_in,
                              void* d_out, int out_size, void* d_ws, size_t ws_size,
                              hipStream_t stream) {
    const unsigned char* links = (const unsigned char*)d_in[0];
    const int* seed = (const int*)d_in[1];
    unsigned char* ws = (unsigned char*)d_ws;

    u64* bitmap = (u64*)(ws + WS_BITMAP);

    clear_bitmap_kernel<<<2048, 256, 0, stream>>>((uint4*)bitmap, 524288);
    mega_kernel<<<513, 1024, 0, stream>>>(links, seed, ws, (uint4*)d_out);
    writeout_sparse<<<1024, 256, 0, stream>>>(ws, (int4*)d_out);
}